// Round 15
// baseline (406.938 us; speedup 1.0000x reference)
//
#include <hip/hip_runtime.h>
#include <hip/hip_bf16.h>
#include <cstddef>

#define H_   22
#define T_   1000
#define B_   64
#define NSEQ (B_ * H_)      // 1408 sequences (B*C, C==22)
#define NPAIR (NSEQ / 2)    // 704 wave-pairs
#define KP   22             // conv out channels
#define TP   10             // pooled time positions
#define POOL 100
#define CSTR 488            // conv hl row stride in fp16 (484 -> 488 = 61 uint4)
#define SEG  10             // temporal segments
#define SEGLEN (T_ / SEG)   // 100
#define WARM 32             // warm-up steps (R14-verified: absmax unchanged)
#define WPB  4              // lstm waves per block

#define WS_HSW   0
#define WS_POOL  61952000
#define WS_WST   62008320   // fp16 [61][22][8] = 21,472 B
#define WS_BNC   62029792   // float4[22] = 352 B

typedef _Float16 half2_t __attribute__((ext_vector_type(2)));

__device__ __forceinline__ float sigm(float x) {
    return __fdividef(1.f, 1.f + __expf(-x));     // saturates correctly
}
__device__ __forceinline__ float tanhfast(float x) {
    return 1.f - __fdividef(2.f, __expf(2.f * x) + 1.f);
}

// one LSTM cell step for one sequence (per-lane: unit hh, 4 gate rows)
__device__ __forceinline__ float lstm_cell(
    float xc, const half2_t* hp, const half2_t w2[4][11],
    const float wih[4], const float bias[4], float& creg)
{
    float a0 = fmaf(xc, wih[0], bias[0]);
    float a1 = fmaf(xc, wih[1], bias[1]);
    float a2 = fmaf(xc, wih[2], bias[2]);
    float a3 = fmaf(xc, wih[3], bias[3]);
    float b0 = 0.f, b1 = 0.f, b2 = 0.f, b3 = 0.f;
    #pragma unroll
    for (int j = 0; j < 6; ++j) {
        a0 = __builtin_amdgcn_fdot2(hp[j], w2[0][j], a0, false);
        a1 = __builtin_amdgcn_fdot2(hp[j], w2[1][j], a1, false);
        a2 = __builtin_amdgcn_fdot2(hp[j], w2[2][j], a2, false);
        a3 = __builtin_amdgcn_fdot2(hp[j], w2[3][j], a3, false);
    }
    #pragma unroll
    for (int j = 6; j < 11; ++j) {
        b0 = __builtin_amdgcn_fdot2(hp[j], w2[0][j], b0, false);
        b1 = __builtin_amdgcn_fdot2(hp[j], w2[1][j], b1, false);
        b2 = __builtin_amdgcn_fdot2(hp[j], w2[2][j], b2, false);
        b3 = __builtin_amdgcn_fdot2(hp[j], w2[3][j], b3, false);
    }
    a0 += b0; a1 += b1; a2 += b2; a3 += b3;
    const float ig = sigm(a0);
    const float fg = sigm(a1);
    const float gg = tanhfast(a2);
    const float og = sigm(a3);
    creg = fmaf(fg, creg, ig * gg);
    return og * tanhfast(creg);
}

// one h-exchange + cell step (per-wave LDS slab, no cross-wave sync)
__device__ __forceinline__ float lstm_step(
    float xc, _Float16* hlw, const uint4* hv, int half, int hh,
    const half2_t w2[4][11], const float wih[4], const float bias[4],
    float& creg)
{
    __builtin_amdgcn_wave_barrier();
    uint4 hr[3];
    hr[0] = hv[0]; hr[1] = hv[1]; hr[2] = hv[2];   // 3x ds_read_b128
    __builtin_amdgcn_wave_barrier();
    const float hn = lstm_cell(xc,
        reinterpret_cast<const half2_t*>(hr), w2, wih, bias, creg);
    hlw[half * 24 + hh] = (_Float16)hn;            // ds_write_b16
    __builtin_amdgcn_wave_barrier();
    return hn;
}

// ---------------------------------------------------------------------------
// Kernel 1 (FROZEN from R14, 257us): batched LSTMs, temporal warm-up split.
// ---------------------------------------------------------------------------
__global__ __launch_bounds__(64 * WPB)
__attribute__((amdgpu_waves_per_eu(4, 4)))
void lstm_k(
    const float* __restrict__ xin,   // [NSEQ][T_]
    const float* __restrict__ W_ih,  // [88]
    const float* __restrict__ W_hh,  // [88][22]
    const float* __restrict__ b_ih,  // [88]
    const float* __restrict__ b_hh,  // [88]
    _Float16* __restrict__ hsw)      // [B_][T_][22][22]
{
    __shared__ __align__(16) _Float16 hl[WPB][2][24];
    const int wid  = threadIdx.x >> 6;             // wave in block
    const int gwv  = blockIdx.x * WPB + wid;       // global wave id
    const int seg  = gwv / NPAIR;                  // 0..SEG-1
    const int pair = gwv - seg * NPAIR;            // 0..703
    const int lane = threadIdx.x & 63;
    const int half = lane >> 5;
    const int hh   = lane & 31;
    if (hh >= H_) return;
    const int seq = pair * 2 + half;
    const int b   = seq / H_;
    const int c   = seq - b * H_;

    half2_t w2[4][11];
    float wih[4], bias[4];
    #pragma unroll
    for (int g = 0; g < 4; ++g) {
        const int row = g * H_ + hh;
        wih[g]  = W_ih[row];
        bias[g] = b_ih[row] + b_hh[row];
        #pragma unroll
        for (int j = 0; j < 11; ++j) {
            half2_t t;
            t[0] = (_Float16)W_hh[row * H_ + 2 * j];
            t[1] = (_Float16)W_hh[row * H_ + 2 * j + 1];
            w2[g][j] = t;
        }
    }

    _Float16* hlw = &hl[wid][0][0];
    hlw[half * 24 + hh] = (_Float16)0.f;                  // h(warm-start) = 0
    if (hh < 2) hlw[half * 24 + H_ + hh] = (_Float16)0.f; // pads [22],[23]
    float creg = 0.f;

    const int t_s = seg * SEGLEN;                  // first stored step
    const int t_e = t_s + SEGLEN;
    const int t_w = (seg == 0) ? 0 : (t_s - WARM); // warm start (mult of 4)

    const float* xp = xin + (size_t)seq * T_;
    _Float16* hout = hsw + ((size_t)b * T_ + t_s) * 484 + c * H_ + hh;
    const uint4* hv = reinterpret_cast<const uint4*>(&hl[wid][half][0]);

    for (int t4 = t_w; t4 < t_s; t4 += 4) {        // warm-up: no stores
        const float4 xq = *reinterpret_cast<const float4*>(xp + t4);
        float xs[4] = {xq.x, xq.y, xq.z, xq.w};
        #pragma unroll
        for (int i = 0; i < 4; ++i)
            lstm_step(xs[i], hlw, hv, half, hh, w2, wih, bias, creg);
    }
    for (int t4 = t_s; t4 < t_e; t4 += 4) {        // stored segment
        const float4 xq = *reinterpret_cast<const float4*>(xp + t4);
        float xs[4] = {xq.x, xq.y, xq.z, xq.w};
        #pragma unroll
        for (int i = 0; i < 4; ++i) {
            const float hn = lstm_step(xs[i], hlw, hv, half, hh,
                                       w2, wih, bias, creg);
            hout[(size_t)i * 484] = (_Float16)hn;
        }
        hout += 4 * 484;
    }
}

// ---------------------------------------------------------------------------
// Kernel 1b: one-time weight prep. conv_w[k][i][r] -> fp16 wst[cch][k][e]
// (dot index dp = r*22+i, cch = dp>>3, e = dp&7, zero-padded to 488), plus
// BN/bias constants bnc[k] = {conv_b, bn_mean, bn_beta, gamma*rsqrt(var+eps)}.
// Removes the per-block div-heavy transform (640 blocks x 10648 div/mods).
// ---------------------------------------------------------------------------
__global__ __launch_bounds__(256) void wprep_k(
    const float* __restrict__ conv_w,  // [22][22][22]
    const float* __restrict__ conv_b,
    const float* __restrict__ bn_g,
    const float* __restrict__ bn_b,
    const float* __restrict__ bn_m,
    const float* __restrict__ bn_v,
    _Float16* __restrict__ wst,        // [61][22][8]
    float4* __restrict__ bnc)          // [22]
{
    const int tid = threadIdx.x;
    for (int e = tid; e < 61 * 22 * 8; e += 256) {
        const int cch = e >> 3 ;                    // combined below
        const int sub = e & 7;
        const int kk  = (e >> 3) % 22;
        const int cc  = (e >> 3) / 22;
        const int dp  = cc * 8 + sub;
        float v = 0.f;
        if (dp < 484) {
            const int r = dp / 22, i2 = dp - r * 22;
            v = conv_w[(kk * 22 + i2) * 22 + r];
        }
        (void)cch;
        wst[(cc * 22 + kk) * 8 + sub] = (_Float16)v;
    }
    if (tid < 22)
        bnc[tid] = make_float4(conv_b[tid], bn_m[tid], bn_b[tid],
                               bn_g[tid] * __frsqrt_rn(bn_v[tid] + 1e-5f));
}

// conv compute for one staged phase: NRT rows {t5 + 10*i}, 1 out-channel k.
template <int NRT>
__device__ __forceinline__ void conv_phase(
    const uint4* __restrict__ wl4, const uint4* __restrict__ hl4,
    int k, int t5, float* __restrict__ acc)
{
    const uint4* wp = wl4 + k;                     // stride 22 per cch
    const uint4* hp[NRT];
    #pragma unroll
    for (int i = 0; i < NRT; ++i) hp[i] = hl4 + (t5 + 10 * i) * 61;
    #pragma unroll 2
    for (int cch = 0; cch < 61; ++cch) {
        const uint4 wv = *wp; wp += 22;
        const half2_t* w2 = reinterpret_cast<const half2_t*>(&wv);
        #pragma unroll
        for (int i = 0; i < NRT; ++i) {
            const uint4 hv = hp[i][cch];
            const half2_t* h2 = reinterpret_cast<const half2_t*>(&hv);
            acc[i] = __builtin_amdgcn_fdot2(h2[0], w2[0], acc[i], false);
            acc[i] = __builtin_amdgcn_fdot2(h2[1], w2[1], acc[i], false);
            acc[i] = __builtin_amdgcn_fdot2(h2[2], w2[2], acc[i], false);
            acc[i] = __builtin_amdgcn_fdot2(h2[3], w2[3], acc[i], false);
        }
    }
}

// ---------------------------------------------------------------------------
// Kernel 2 v2: conv + bias + ELU + BN + AvgPool. One block per (b,p).
// R15: weights pre-transformed (vector copy from ws), div-free h staging
// (row = tid>>7 pairs, col = tid&127), compile-time NRT phase bodies with
// pointer-increment addressing (~29 insts / 16 dot2, was ~58).
// ---------------------------------------------------------------------------
__global__ __launch_bounds__(256) void conv_k(
    const _Float16* __restrict__ hsw,  // [B_][T_][22][22]
    const _Float16* __restrict__ wst,  // [61][22][8]
    const float4* __restrict__ bnc,    // [22]
    float* __restrict__ pooled)        // [B_][22][10]
{
    __shared__ __align__(16) _Float16 wl[61 * 22 * 8];  // 21,472 B
    __shared__ __align__(16) _Float16 hl[40 * CSTR];    // 39,040 B
    __shared__ float pp[22 * TP];

    const int tid = threadIdx.x;
    const int b = blockIdx.x / TP;
    const int p = blockIdx.x - b * TP;

    // vector-copy staged weights (1342 uint4, coalesced)
    {
        const uint4* s4 = reinterpret_cast<const uint4*>(wst);
        uint4* d4 = reinterpret_cast<uint4*>(wl);
        for (int i = tid; i < 1342; i += 256) d4[i] = s4[i];
    }

    const int k  = tid % 22;          // out channel
    const int t5 = tid / 22;          // row group (0..9 valid)
    const bool act = (tid < 220);
    const float4 bc = bnc[k];         // {cb, mean, beta, inv}

    float poolsum = 0.f;
    const _Float16* src = hsw + ((size_t)b * T_ + (size_t)p * POOL) * 484;
    const uint4* wl4 = reinterpret_cast<const uint4*>(wl);
    const uint4* hl4 = reinterpret_cast<const uint4*>(hl);

    const int rsel = tid >> 7;        // 0/1: which row of each staging pair
    const int col  = tid & 127;       // uint2 column (0..120 valid)

    for (int ph = 0; ph < 3; ++ph) {
        const int rows = (ph == 2) ? 20 : 40;
        const uint2* gsrc = reinterpret_cast<const uint2*>(src + (size_t)(ph * 40) * 484);
        // div-free staging: 2 rows per pass
        for (int r = rsel; r < rows; r += 2) {
            uint2* drow = reinterpret_cast<uint2*>(&hl[r * CSTR]);
            if (col < 121)      drow[col] = gsrc[(size_t)r * 121 + col];
            else if (col < 123) drow[121 + (col - 121)] = make_uint2(0u, 0u); // pad 484..487
        }
        __syncthreads();

        if (act) {
            float acc[4] = {0.f, 0.f, 0.f, 0.f};
            if (ph < 2) conv_phase<4>(wl4, hl4, k, t5, acc);
            else        conv_phase<2>(wl4, hl4, k, t5, acc);
            const int nv = (ph == 2) ? 2 : 4;
            for (int i = 0; i < nv; ++i) {
                const float s = acc[i] + bc.x;
                const float e = (s > 0.f) ? s : (__expf(s) - 1.f);
                poolsum += fmaf(e - bc.y, bc.w, bc.z);
            }
        }
        __syncthreads();
    }

    if (act) pp[k * TP + t5] = poolsum;
    __syncthreads();
    if (tid < 22) {
        float s = 0.f;
        #pragma unroll
        for (int q = 0; q < TP; ++q) s += pp[tid * TP + q];
        pooled[((size_t)b * 22 + tid) * TP + p] = s * 0.01f;
    }
}

// ---------------------------------------------------------------------------
// Kernel 3: FC [64,220] x [220,4]^T + bias -> fp32 out. One thread per output.
// ---------------------------------------------------------------------------
__global__ __launch_bounds__(256) void fc_k(
    const float* __restrict__ pooled,  // [64][220] (idx = k*10+p)
    const float* __restrict__ fc_w,    // [4][220]
    const float* __restrict__ fc_b,    // [4]
    float* __restrict__ out)           // [64][4]
{
    const int tid = threadIdx.x;
    const int b = tid >> 2, n = tid & 3;
    const float* pv = pooled + b * 220;
    const float* wv = fc_w + n * 220;
    float s = fc_b[n];
    #pragma unroll 4
    for (int j = 0; j < 220; ++j)
        s = fmaf(pv[j], wv[j], s);
    out[tid] = s;
}

extern "C" void kernel_launch(void* const* d_in, const int* in_sizes, int n_in,
                              void* d_out, int out_size, void* d_ws, size_t ws_size,
                              hipStream_t stream) {
    const float* xin    = (const float*)d_in[0];
    const float* W_ih   = (const float*)d_in[1];
    const float* W_hh   = (const float*)d_in[2];
    const float* b_ih   = (const float*)d_in[3];
    const float* b_hh   = (const float*)d_in[4];
    const float* conv_w = (const float*)d_in[5];
    const float* conv_b = (const float*)d_in[6];
    const float* bn_g   = (const float*)d_in[7];
    const float* bn_b   = (const float*)d_in[8];
    const float* bn_m   = (const float*)d_in[9];
    const float* bn_v   = (const float*)d_in[10];
    const float* fc_w   = (const float*)d_in[11];
    const float* fc_b   = (const float*)d_in[12];

    char* ws = (char*)d_ws;
    _Float16* hsw   = (_Float16*)(ws + WS_HSW);
    float*    pooled= (float*)   (ws + WS_POOL);
    _Float16* wst   = (_Float16*)(ws + WS_WST);
    float4*   bnc   = (float4*)  (ws + WS_BNC);

    wprep_k<<<1, 256, 0, stream>>>(conv_w, conv_b, bn_g, bn_b, bn_m, bn_v,
                                   wst, bnc);
    lstm_k<<<NPAIR * SEG / WPB, 64 * WPB, 0, stream>>>(xin, W_ih, W_hh,
                                                       b_ih, b_hh, hsw);
    conv_k<<<B_ * TP, 256, 0, stream>>>(hsw, wst, bnc, pooled);
    fc_k<<<1, 256, 0, stream>>>(pooled, fc_w, fc_b, (float*)d_out);
}